// Round 6
// baseline (186.278 us; speedup 1.0000x reference)
//
#include <hip/hip_runtime.h>

// VP_lattice reverse step, B = 2^20 rows. Round-5b: max memory-level
// parallelism (R5 compile fix: __builtin_nontemporal_* needs clang native
// vector types, not HIP_vector_type). 4 rows/thread => all streams
// 16B-aligned per thread: 27 independent dwordx4 loads (27KB/wave) in one
// batch, short fp32 chains (R3-validated closed-form sqrtm), one barrier,
// nontemporal hints on the one-touch streams.

#define NUM_STEPS 1000

typedef float  f4 __attribute__((ext_vector_type(4)));
typedef int    i4 __attribute__((ext_vector_type(4)));

__global__ __launch_bounds__(256) void vp_lattice_kernel(
    const float* __restrict__ lt,
    const float* __restrict__ pl0,
    const float* __restrict__ plat,
    const float* __restrict__ alpha_bars,
    const float* __restrict__ betas,
    const float* __restrict__ sigmas,
    const float* __restrict__ z_noise,
    const int*   __restrict__ t,
    float* __restrict__ out,
    int nquad)                      // n/4
{
    __shared__ float sCoef[NUM_STEPS + 1];
    __shared__ float sScale[NUM_STEPS + 1];
    __shared__ float sSig[NUM_STEPS + 1];
    {
        float beta_last = betas[NUM_STEPS - 1];          // betas[-2]
        for (int j = threadIdx.x; j <= NUM_STEPS; j += 256) {
            float alpha = 1.0f - fminf(betas[j], beta_last);
            sCoef[j]  = 1.0f / sqrtf(alpha + 1e-8f);
            sScale[j] = (1.0f - alpha) / sqrtf(1.0f - alpha_bars[j] + 1e-8f);
            sSig[j]   = (j > 1) ? sigmas[j] : 0.0f;
        }
    }

    int gid = blockIdx.x * blockDim.x + threadIdx.x;
    if (gid >= nquad) { __syncthreads(); return; }

    // ---- issue ALL loads up front: 27 independent dwordx4 + 1 int4 ----
    const f4* plat4 = reinterpret_cast<const f4*>(plat)    + (size_t)gid * 9;
    const f4* lt4   = reinterpret_cast<const f4*>(lt)      + (size_t)gid * 6;
    const f4* pl4   = reinterpret_cast<const f4*>(pl0)     + (size_t)gid * 6;
    const f4* zn4   = reinterpret_cast<const f4*>(z_noise) + (size_t)gid * 6;
    i4 tt = reinterpret_cast<const i4*>(t)[gid];

    f4 A4[9], L4[6], P4[6], Z4[6];
#pragma unroll
    for (int j = 0; j < 9; ++j) A4[j] = __builtin_nontemporal_load(&plat4[j]);
#pragma unroll
    for (int j = 0; j < 6; ++j) L4[j] = __builtin_nontemporal_load(&lt4[j]);
#pragma unroll
    for (int j = 0; j < 6; ++j) P4[j] = __builtin_nontemporal_load(&pl4[j]);
#pragma unroll
    for (int j = 0; j < 6; ++j) Z4[j] = __builtin_nontemporal_load(&zn4[j]);

    const float* Af = reinterpret_cast<const float*>(A4);   // 36 floats, 4 rows
    const float* Lf = reinterpret_cast<const float*>(L4);   // 24 floats
    const float* Pf = reinterpret_cast<const float*>(P4);
    const float* Zf = reinterpret_cast<const float*>(Z4);
    int tis[4] = {tt.x, tt.y, tt.z, tt.w};

    __syncthreads();        // table ready (also the only barrier)

    float ov[24];
#pragma unroll
    for (int r = 0; r < 4; ++r) {
        const float* A = Af + r * 9;
        float a00 = A[0], a01 = A[1], a02 = A[2];
        float a10 = A[3], a11 = A[4], a12 = A[5];
        float a20 = A[6], a21 = A[7], a22 = A[8];

        // M = A^T A (symmetric PSD)
        float m00 = a00*a00 + a10*a10 + a20*a20;
        float m01 = a00*a01 + a10*a11 + a20*a21;
        float m02 = a00*a02 + a10*a12 + a20*a22;
        float m11 = a01*a01 + a11*a11 + a21*a21;
        float m12 = a01*a02 + a11*a12 + a21*a22;
        float m22 = a02*a02 + a12*a12 + a22*a22;

        // eigenvalues: cancellation-free trig form (validated R3)
        float q  = (m00 + m11 + m22) * (1.0f/3.0f);
        float b00 = m00 - q, b11 = m11 - q, b22 = m22 - q;
        float p1 = m01*m01 + m02*m02 + m12*m12;
        float p2 = b00*b00 + b11*b11 + b22*b22 + 2.0f*p1;
        float p  = sqrtf(p2 * (1.0f/6.0f));
        float detB = b00*(b11*b22 - m12*m12)
                   - m01*(m01*b22 - m12*m02)
                   + m02*(m01*m12 - b11*m02);
        float pinv = 1.0f / fmaxf(p, 1e-20f);
        float rr = 0.5f * detB * pinv * pinv * pinv;
        rr = fminf(fmaxf(rr, -1.0f), 1.0f);
        float phi = acosf(rr) * (1.0f/3.0f);
        float mu1 = q + 2.0f*p*cosf(phi);
        float mu3 = q + 2.0f*p*cosf(phi + 2.0943951023931953f);
        float mu2 = 3.0f*q - mu1 - mu3;
        float l1 = sqrtf(fmaxf(mu1, 0.0f));
        float l2 = sqrtf(fmaxf(mu2, 0.0f));
        float l3 = sqrtf(fmaxf(mu3, 0.0f));

        // U = sqrtm(M), Hoger-Carlson inverse-free
        float IU   = l1 + l2 + l3;
        float IIU  = l1*(l2 + l3) + l2*l3;
        float IIIU = l1*l2*l3;
        float denom = (l1 + l2) * (l1 + l3) * (l2 + l3);
        float dinv  = 1.0f / fmaxf(denom, 1e-25f);
        float sd = (IU*IU - IIU) * dinv;
        float td = IU * IIIU * dinv;
        float nd = -dinv;

        float mm00 = m00*m00 + m01*m01 + m02*m02;
        float mm01 = m00*m01 + m01*m11 + m02*m12;
        float mm02 = m00*m02 + m01*m12 + m02*m22;
        float mm11 = m01*m01 + m11*m11 + m12*m12;
        float mm12 = m01*m02 + m11*m12 + m12*m22;
        float mm22 = m02*m02 + m12*m12 + m22*m22;

        float vv[6];
        vv[0] = nd*mm00 + sd*m00 + td;
        vv[1] = nd*mm01 + sd*m01;
        vv[2] = nd*mm02 + sd*m02;
        vv[3] = nd*mm11 + sd*m11 + td;
        vv[4] = nd*mm12 + sd*m12;
        vv[5] = nd*mm22 + sd*m22 + td;

        int ti = tis[r];
        float coef  = sCoef[ti];
        float scale = sScale[ti];
        float sig   = sSig[ti];
#pragma unroll
        for (int c = 0; c < 6; ++c) {
            float lc = Lf[r*6 + c];
            float pn = lc - 0.5f * (vv[c] + Pf[r*6 + c]);
            ov[r*6 + c] = coef * (lc - scale * pn) + sig * Zf[r*6 + c];
        }
    }

    f4* out4 = reinterpret_cast<f4*>(out) + (size_t)gid * 6;
#pragma unroll
    for (int j = 0; j < 6; ++j) {
        f4 o = {ov[4*j], ov[4*j+1], ov[4*j+2], ov[4*j+3]};
        __builtin_nontemporal_store(o, &out4[j]);
    }
}

extern "C" void kernel_launch(void* const* d_in, const int* in_sizes, int n_in,
                              void* d_out, int out_size, void* d_ws, size_t ws_size,
                              hipStream_t stream) {
    const float* lt         = (const float*)d_in[0];
    const float* pl0        = (const float*)d_in[1];
    const float* plat       = (const float*)d_in[2];
    const float* alpha_bars = (const float*)d_in[3];
    const float* betas      = (const float*)d_in[4];
    const float* sigmas     = (const float*)d_in[5];
    const float* z_noise    = (const float*)d_in[6];
    const int*   t          = (const int*)d_in[7];
    float* out = (float*)d_out;

    int n = in_sizes[0] / 6;        // B rows (2^20, multiple of 1024)
    int nquad = n / 4;              // 4 rows per thread
    int block = 256;
    int grid = (nquad + block - 1) / block;
    vp_lattice_kernel<<<grid, block, 0, stream>>>(
        lt, pl0, plat, alpha_bars, betas, sigmas, z_noise, t, out, nquad);
}

// Round 7
// 168.944 us; speedup vs baseline: 1.1026x; 1.1026x over previous
//
#include <hip/hip_runtime.h>

// VP_lattice reverse step, B = 2^20 rows. Round-7: producer/consumer split.
// R1-R6: dispatch pinned at ~44-51us (~3.1 TB/s combined) across precision,
// ILP, coalescing, gather location, occupancy, nt hints. Hypothesis: mixing
// 5 read streams + gathers + heavy VALU in one dispatch halves the memory
// service rate vs a copy-shaped kernel. Split:
//   K1: plat -> vec (d_ws). 2 streams + VALU (validated fp32 closed-form).
//   K2: lt/pl0/vec/z/t -> out. Pure elementwise, copy-shaped.
// Fallback: fused R3-style kernel if ws_size is too small (host-constant
// branch, graph-capture safe).

#define NUM_STEPS 1000

typedef float f4 __attribute__((ext_vector_type(4)));

// ---------- shared device helper: vec[6] = sqrtm(A^T A) upper triangle ----
__device__ __forceinline__ void sqrtm_vec(const float* A, float* vv)
{
    float a00 = A[0], a01 = A[1], a02 = A[2];
    float a10 = A[3], a11 = A[4], a12 = A[5];
    float a20 = A[6], a21 = A[7], a22 = A[8];

    // M = A^T A (symmetric PSD)
    float m00 = a00*a00 + a10*a10 + a20*a20;
    float m01 = a00*a01 + a10*a11 + a20*a21;
    float m02 = a00*a02 + a10*a12 + a20*a22;
    float m11 = a01*a01 + a11*a11 + a21*a21;
    float m12 = a01*a02 + a11*a12 + a21*a22;
    float m22 = a02*a02 + a12*a12 + a22*a22;

    // eigenvalues: cancellation-free trig form (validated R3)
    float q  = (m00 + m11 + m22) * (1.0f/3.0f);
    float b00 = m00 - q, b11 = m11 - q, b22 = m22 - q;
    float p1 = m01*m01 + m02*m02 + m12*m12;
    float p2 = b00*b00 + b11*b11 + b22*b22 + 2.0f*p1;
    float p  = sqrtf(p2 * (1.0f/6.0f));
    float detB = b00*(b11*b22 - m12*m12)
               - m01*(m01*b22 - m12*m02)
               + m02*(m01*m12 - b11*m02);
    float pinv = 1.0f / fmaxf(p, 1e-20f);
    float rr = 0.5f * detB * pinv * pinv * pinv;
    rr = fminf(fmaxf(rr, -1.0f), 1.0f);
    float phi = acosf(rr) * (1.0f/3.0f);
    float mu1 = q + 2.0f*p*cosf(phi);
    float mu3 = q + 2.0f*p*cosf(phi + 2.0943951023931953f);
    float mu2 = 3.0f*q - mu1 - mu3;
    float l1 = sqrtf(fmaxf(mu1, 0.0f));
    float l2 = sqrtf(fmaxf(mu2, 0.0f));
    float l3 = sqrtf(fmaxf(mu3, 0.0f));

    // U = sqrtm(M), Hoger-Carlson inverse-free
    float IU   = l1 + l2 + l3;
    float IIU  = l1*(l2 + l3) + l2*l3;
    float IIIU = l1*l2*l3;
    float denom = (l1 + l2) * (l1 + l3) * (l2 + l3);
    float dinv  = 1.0f / fmaxf(denom, 1e-25f);
    float sd = (IU*IU - IIU) * dinv;
    float td = IU * IIIU * dinv;
    float nd = -dinv;

    float mm00 = m00*m00 + m01*m01 + m02*m02;
    float mm01 = m00*m01 + m01*m11 + m02*m12;
    float mm02 = m00*m02 + m01*m12 + m02*m22;
    float mm11 = m01*m01 + m11*m11 + m12*m12;
    float mm12 = m01*m02 + m11*m12 + m12*m22;
    float mm22 = m02*m02 + m12*m12 + m22*m22;

    vv[0] = nd*mm00 + sd*m00 + td;
    vv[1] = nd*mm01 + sd*m01;
    vv[2] = nd*mm02 + sd*m02;
    vv[3] = nd*mm11 + sd*m11 + td;
    vv[4] = nd*mm12 + sd*m12;
    vv[5] = nd*mm22 + sd*m22 + td;
}

// ---------- K1: plat -> vec (producer; 2 streams + VALU) ----------
__global__ __launch_bounds__(256) void k1_vec(
    const float* __restrict__ plat,
    float* __restrict__ vec,
    int nquad)                       // n/4
{
    int gid = blockIdx.x * blockDim.x + threadIdx.x;
    if (gid >= nquad) return;

    const f4* plat4 = reinterpret_cast<const f4*>(plat) + (size_t)gid * 9;
    f4 A4[9];
#pragma unroll
    for (int j = 0; j < 9; ++j) A4[j] = plat4[j];
    const float* Af = reinterpret_cast<const float*>(A4);

    float ov[24];
#pragma unroll
    for (int r = 0; r < 4; ++r) sqrtm_vec(Af + r * 9, ov + r * 6);

    f4* vec4 = reinterpret_cast<f4*>(vec) + (size_t)gid * 6;
#pragma unroll
    for (int j = 0; j < 6; ++j) {
        f4 o = {ov[4*j], ov[4*j+1], ov[4*j+2], ov[4*j+3]};
        vec4[j] = o;
    }
}

// ---------- K2: elementwise consumer (copy-shaped) ----------
__global__ __launch_bounds__(256) void k2_epilogue(
    const float* __restrict__ lt,
    const float* __restrict__ pl0,
    const float* __restrict__ vec,
    const float* __restrict__ z_noise,
    const int*   __restrict__ t,
    const float* __restrict__ alpha_bars,
    const float* __restrict__ betas,
    const float* __restrict__ sigmas,
    float* __restrict__ out,
    int npair)                       // n/2
{
    int gid = blockIdx.x * blockDim.x + threadIdx.x;
    if (gid >= npair) return;

    const f4* lt4 = reinterpret_cast<const f4*>(lt)      + (size_t)gid * 3;
    const f4* pl4 = reinterpret_cast<const f4*>(pl0)     + (size_t)gid * 3;
    const f4* vc4 = reinterpret_cast<const f4*>(vec)     + (size_t)gid * 3;
    const f4* zn4 = reinterpret_cast<const f4*>(z_noise) + (size_t)gid * 3;
    f4 L4[3], P4[3], V4[3], Z4[3];
#pragma unroll
    for (int j = 0; j < 3; ++j) L4[j] = lt4[j];
#pragma unroll
    for (int j = 0; j < 3; ++j) P4[j] = pl4[j];
#pragma unroll
    for (int j = 0; j < 3; ++j) V4[j] = vc4[j];
#pragma unroll
    for (int j = 0; j < 3; ++j) Z4[j] = zn4[j];
    int2 tt = reinterpret_cast<const int2*>(t)[gid];

    const float* Lf = reinterpret_cast<const float*>(L4);
    const float* Pf = reinterpret_cast<const float*>(P4);
    const float* Vf = reinterpret_cast<const float*>(V4);
    const float* Zf = reinterpret_cast<const float*>(Z4);

    float beta_last = betas[NUM_STEPS - 1];   // betas[-2], scalar (uniform)
    float ov[12];
#pragma unroll
    for (int r = 0; r < 2; ++r) {
        int ti = (r == 0) ? tt.x : tt.y;
        float alpha = 1.0f - fminf(betas[ti], beta_last);
        float ab    = alpha_bars[ti];
        float sig   = (ti > 1) ? sigmas[ti] : 0.0f;
        float coef  = 1.0f / sqrtf(alpha + 1e-8f);
        float scale = (1.0f - alpha) / sqrtf(1.0f - ab + 1e-8f);
#pragma unroll
        for (int c = 0; c < 6; ++c) {
            float lc = Lf[r*6 + c];
            float pn = lc - 0.5f * (Vf[r*6 + c] + Pf[r*6 + c]);
            ov[r*6 + c] = coef * (lc - scale * pn) + sig * Zf[r*6 + c];
        }
    }

    f4* out4 = reinterpret_cast<f4*>(out) + (size_t)gid * 3;
#pragma unroll
    for (int j = 0; j < 3; ++j) {
        f4 o = {ov[4*j], ov[4*j+1], ov[4*j+2], ov[4*j+3]};
        out4[j] = o;
    }
}

// ---------- fallback: fused (R1-structure, fp32) ----------
__global__ __launch_bounds__(256) void fused_kernel(
    const float* __restrict__ lt,
    const float* __restrict__ pl0,
    const float* __restrict__ plat,
    const float* __restrict__ alpha_bars,
    const float* __restrict__ betas,
    const float* __restrict__ sigmas,
    const float* __restrict__ z_noise,
    const int*   __restrict__ t,
    float* __restrict__ out,
    int n)
{
    int i = blockIdx.x * blockDim.x + threadIdx.x;
    if (i >= n) return;

    size_t b9 = (size_t)i * 9;
    float A[9];
#pragma unroll
    for (int j = 0; j < 9; ++j) A[j] = plat[b9 + j];
    float vv[6];
    sqrtm_vec(A, vv);

    int ti = t[i];
    float beta_last = betas[NUM_STEPS - 1];
    float alpha = 1.0f - fminf(betas[ti], beta_last);
    float coef  = 1.0f / sqrtf(alpha + 1e-8f);
    float scale = (1.0f - alpha) / sqrtf(1.0f - alpha_bars[ti] + 1e-8f);
    float sig   = (ti > 1) ? sigmas[ti] : 0.0f;

    size_t b6 = (size_t)i * 6;
#pragma unroll
    for (int c = 0; c < 6; ++c) {
        float lc = lt[b6 + c];
        float pn = lc - 0.5f * (vv[c] + pl0[b6 + c]);
        out[b6 + c] = coef * (lc - scale * pn) + sig * z_noise[b6 + c];
    }
}

extern "C" void kernel_launch(void* const* d_in, const int* in_sizes, int n_in,
                              void* d_out, int out_size, void* d_ws, size_t ws_size,
                              hipStream_t stream) {
    const float* lt         = (const float*)d_in[0];
    const float* pl0        = (const float*)d_in[1];
    const float* plat       = (const float*)d_in[2];
    const float* alpha_bars = (const float*)d_in[3];
    const float* betas      = (const float*)d_in[4];
    const float* sigmas     = (const float*)d_in[5];
    const float* z_noise    = (const float*)d_in[6];
    const int*   t          = (const int*)d_in[7];
    float* out = (float*)d_out;

    int n = in_sizes[0] / 6;                 // B rows (2^20, mult of 1024)
    size_t vec_bytes = (size_t)n * 6 * sizeof(float);

    if (ws_size >= vec_bytes) {
        float* vec = (float*)d_ws;
        int nquad = n / 4;
        k1_vec<<<(nquad + 255) / 256, 256, 0, stream>>>(plat, vec, nquad);
        int npair = n / 2;
        k2_epilogue<<<(npair + 255) / 256, 256, 0, stream>>>(
            lt, pl0, vec, z_noise, t, alpha_bars, betas, sigmas, out, npair);
    } else {
        fused_kernel<<<(n + 255) / 256, 256, 0, stream>>>(
            lt, pl0, plat, alpha_bars, betas, sigmas, z_noise, t, out, n);
    }
}

// Round 8
// 155.048 us; speedup vs baseline: 1.2014x; 1.0896x over previous
//
#include <hip/hip_runtime.h>

// VP_lattice reverse step, B = 2^20 rows. Round-8: cleanest max-MLP fused
// kernel. R1-R7 summary: every read-containing kernel shape pins at
// ~3.0-3.2 TB/s combined service rate (while the harness's own 268MB fill
// runs 6.6 TB/s writes) => suspected read-path (cross-XCD L2/L3 coherent
// service) ceiling. This round: fp32 short chains (R3-validated closed-form
// sqrtm) x 2 rows/thread x all-float4 streams x no LDS/no barrier x direct
// table gathers. If this also lands ~44us, the ceiling is confirmed across
// all software axes.

#define NUM_STEPS 1000

typedef float f4 __attribute__((ext_vector_type(4)));
typedef float f2 __attribute__((ext_vector_type(2)));

__device__ __forceinline__ void sqrtm_vec(const float* A, float* vv)
{
    float a00 = A[0], a01 = A[1], a02 = A[2];
    float a10 = A[3], a11 = A[4], a12 = A[5];
    float a20 = A[6], a21 = A[7], a22 = A[8];

    // M = A^T A (symmetric PSD)
    float m00 = a00*a00 + a10*a10 + a20*a20;
    float m01 = a00*a01 + a10*a11 + a20*a21;
    float m02 = a00*a02 + a10*a12 + a20*a22;
    float m11 = a01*a01 + a11*a11 + a21*a21;
    float m12 = a01*a02 + a11*a12 + a21*a22;
    float m22 = a02*a02 + a12*a12 + a22*a22;

    // eigenvalues: cancellation-free trig form (validated R3)
    float q  = (m00 + m11 + m22) * (1.0f/3.0f);
    float b00 = m00 - q, b11 = m11 - q, b22 = m22 - q;
    float p1 = m01*m01 + m02*m02 + m12*m12;
    float p2 = b00*b00 + b11*b11 + b22*b22 + 2.0f*p1;
    float p  = sqrtf(p2 * (1.0f/6.0f));
    float detB = b00*(b11*b22 - m12*m12)
               - m01*(m01*b22 - m12*m02)
               + m02*(m01*m12 - b11*m02);
    float pinv = 1.0f / fmaxf(p, 1e-20f);
    float rr = 0.5f * detB * pinv * pinv * pinv;
    rr = fminf(fmaxf(rr, -1.0f), 1.0f);
    float phi = acosf(rr) * (1.0f/3.0f);
    float mu1 = q + 2.0f*p*cosf(phi);
    float mu3 = q + 2.0f*p*cosf(phi + 2.0943951023931953f);
    float mu2 = 3.0f*q - mu1 - mu3;
    float l1 = sqrtf(fmaxf(mu1, 0.0f));
    float l2 = sqrtf(fmaxf(mu2, 0.0f));
    float l3 = sqrtf(fmaxf(mu3, 0.0f));

    // U = sqrtm(M), Hoger-Carlson inverse-free
    float IU   = l1 + l2 + l3;
    float IIU  = l1*(l2 + l3) + l2*l3;
    float IIIU = l1*l2*l3;
    float denom = (l1 + l2) * (l1 + l3) * (l2 + l3);
    float dinv  = 1.0f / fmaxf(denom, 1e-25f);
    float sd = (IU*IU - IIU) * dinv;
    float td = IU * IIIU * dinv;
    float nd = -dinv;

    float mm00 = m00*m00 + m01*m01 + m02*m02;
    float mm01 = m00*m01 + m01*m11 + m02*m12;
    float mm02 = m00*m02 + m01*m12 + m02*m22;
    float mm11 = m01*m01 + m11*m11 + m12*m12;
    float mm12 = m01*m02 + m11*m12 + m12*m22;
    float mm22 = m02*m02 + m12*m12 + m22*m22;

    vv[0] = nd*mm00 + sd*m00 + td;
    vv[1] = nd*mm01 + sd*m01;
    vv[2] = nd*mm02 + sd*m02;
    vv[3] = nd*mm11 + sd*m11 + td;
    vv[4] = nd*mm12 + sd*m12;
    vv[5] = nd*mm22 + sd*m22 + td;
}

__global__ __launch_bounds__(256) void vp_lattice_kernel(
    const float* __restrict__ lt,
    const float* __restrict__ pl0,
    const float* __restrict__ plat,
    const float* __restrict__ alpha_bars,
    const float* __restrict__ betas,
    const float* __restrict__ sigmas,
    const float* __restrict__ z_noise,
    const int*   __restrict__ t,
    float* __restrict__ out,
    int npair)                      // n/2
{
    int gid = blockIdx.x * blockDim.x + threadIdx.x;
    if (gid >= npair) return;

    // ---- issue all loads up front: 9 f4 + 9 f2 + 1 int2, all independent --
    const f4* lt4 = reinterpret_cast<const f4*>(lt)      + (size_t)gid * 3;
    const f4* pl4 = reinterpret_cast<const f4*>(pl0)     + (size_t)gid * 3;
    const f4* zn4 = reinterpret_cast<const f4*>(z_noise) + (size_t)gid * 3;
    const f2* pp  = reinterpret_cast<const f2*>(plat)    + (size_t)gid * 9;

    f4 L4[3], P4[3], Z4[3];
    f2 A2[9];
#pragma unroll
    for (int j = 0; j < 3; ++j) L4[j] = lt4[j];
#pragma unroll
    for (int j = 0; j < 3; ++j) P4[j] = pl4[j];
#pragma unroll
    for (int j = 0; j < 3; ++j) Z4[j] = zn4[j];
#pragma unroll
    for (int j = 0; j < 9; ++j) A2[j] = pp[j];
    int2 tt = reinterpret_cast<const int2*>(t)[gid];

    const float* Lf = reinterpret_cast<const float*>(L4);
    const float* Pf = reinterpret_cast<const float*>(P4);
    const float* Zf = reinterpret_cast<const float*>(Z4);
    const float* Af = reinterpret_cast<const float*>(A2);   // 18 floats

    float beta_last = betas[NUM_STEPS - 1];   // betas[-2] (uniform scalar)

    float ov[12];
#pragma unroll
    for (int r = 0; r < 2; ++r) {
        float vv[6];
        sqrtm_vec(Af + r * 9, vv);

        int ti = (r == 0) ? tt.x : tt.y;
        float alpha = 1.0f - fminf(betas[ti], beta_last);
        float ab    = alpha_bars[ti];
        float sig   = (ti > 1) ? sigmas[ti] : 0.0f;
        float coef  = 1.0f / sqrtf(alpha + 1e-8f);
        float scale = (1.0f - alpha) / sqrtf(1.0f - ab + 1e-8f);
#pragma unroll
        for (int c = 0; c < 6; ++c) {
            float lc = Lf[r*6 + c];
            float pn = lc - 0.5f * (vv[c] + Pf[r*6 + c]);
            ov[r*6 + c] = coef * (lc - scale * pn) + sig * Zf[r*6 + c];
        }
    }

    f4* out4 = reinterpret_cast<f4*>(out) + (size_t)gid * 3;
#pragma unroll
    for (int j = 0; j < 3; ++j) {
        f4 o = {ov[4*j], ov[4*j+1], ov[4*j+2], ov[4*j+3]};
        out4[j] = o;
    }
}

extern "C" void kernel_launch(void* const* d_in, const int* in_sizes, int n_in,
                              void* d_out, int out_size, void* d_ws, size_t ws_size,
                              hipStream_t stream) {
    const float* lt         = (const float*)d_in[0];
    const float* pl0        = (const float*)d_in[1];
    const float* plat       = (const float*)d_in[2];
    const float* alpha_bars = (const float*)d_in[3];
    const float* betas      = (const float*)d_in[4];
    const float* sigmas     = (const float*)d_in[5];
    const float* z_noise    = (const float*)d_in[6];
    const int*   t          = (const int*)d_in[7];
    float* out = (float*)d_out;

    int n = in_sizes[0] / 6;        // B rows (2^20)
    int npair = n / 2;              // 2 rows per thread
    int block = 256;
    int grid = (npair + block - 1) / block;
    vp_lattice_kernel<<<grid, block, 0, stream>>>(
        lt, pl0, plat, alpha_bars, betas, sigmas, z_noise, t, out, npair);
}